// Round 12
// baseline (403.304 us; speedup 1.0000x reference)
//
#include <hip/hip_runtime.h>
#include <stdint.h>

// Problem constants (B=256, L=2048, H=64, TE=64)
#define NB 256
#define NL 2048

typedef __attribute__((ext_vector_type(8))) short short8;
typedef __attribute__((ext_vector_type(4))) float f32x4;
#define MFMA16(a,b,c) __builtin_amdgcn_mfma_f32_16x16x32_bf16(a,b,c,0,0,0)

// ---------- bf16 helpers ----------
// R16: gates into scan (371->334). R17 spill 484. R18/19: 317 best.
// R20/R22/R23: occupancy hints => hipcc pins VGPR=64 => spill. CLOSED.
// R24 head async-gather neutral; R25 head global-A regressed (strided
//      half-line reads) — head reverted to R15 shape (best, ~150us).
// R26: scan — projection folded into gate weights on device
//      (z_pre = [tenc|x3]·(Wz·P)^T + (bz+Wz·pb)): s_inp deleted,
//      G2+GATES merged (GZH), carry replicated across all 8 waves with
//      double-buffered s_H => 2 barriers/segment, LDS 56.6KB (<64KB
//      co-residency test).
static __device__ __forceinline__ unsigned short f2bf(float f) {
    union { float f; uint32_t u; } v; v.f = f;
    uint32_t u = v.u;
    uint32_t r = u + 0x7fffu + ((u >> 16) & 1u);
    return (unsigned short)(r >> 16);
}
static __device__ __forceinline__ float bflo(uint32_t u) {
    union { uint32_t u; float f; } v; v.u = u << 16; return v.f;
}
static __device__ __forceinline__ float bfhi(uint32_t u) {
    union { uint32_t u; float f; } v; v.u = u & 0xffff0000u; return v.f;
}
#if __has_builtin(__builtin_amdgcn_cvt_pk_bf16_f32)
typedef __attribute__((ext_vector_type(2))) __bf16 bf16x2_t;
static __device__ __forceinline__ uint32_t pk2(float lo, float hi) {
    union { bf16x2_t v; uint32_t u; } c;
    c.v = __builtin_amdgcn_cvt_pk_bf16_f32(lo, hi);
    return c.u;
}
static __device__ __forceinline__ unsigned short bf1(float v) {
    union { bf16x2_t v; uint32_t u; } c;
    c.v = __builtin_amdgcn_cvt_pk_bf16_f32(v, v);
    return (unsigned short)(c.u & 0xffffu);
}
#else
static __device__ __forceinline__ uint32_t pk2(float lo, float hi) {
    return ((uint32_t)f2bf(hi) << 16) | (uint32_t)f2bf(lo);
}
static __device__ __forceinline__ unsigned short bf1(float v) { return f2bf(v); }
#endif
static __device__ __forceinline__ short8 frag8(const float* p) {
    short8 r;
#pragma unroll
    for (int j = 0; j < 8; ++j) r[j] = (short)f2bf(p[j]);
    return r;
}

// LDS-only barrier: global stores/loads stay in flight across it.
static __device__ __forceinline__ void barrier_lds() {
    asm volatile("s_waitcnt lgkmcnt(0)" ::: "memory");
    __builtin_amdgcn_s_barrier();
}

// =====================================================================
// kernel 0: fold gate weights — G = W·P (64x67 fp32), b' = b + W·pb.
// One combo (dir,gate) per block of 64 threads; runs once per launch.
// =====================================================================
__global__ __launch_bounds__(64) void fold_weights(
    const float* __restrict__ fpw, const float* __restrict__ fpb,
    const float* __restrict__ bpw, const float* __restrict__ bpb,
    const float* __restrict__ fwz, const float* __restrict__ fbz,
    const float* __restrict__ fwh, const float* __restrict__ fbh,
    const float* __restrict__ bwz, const float* __restrict__ bbz,
    const float* __restrict__ bwh, const float* __restrict__ bbh,
    float* __restrict__ gw, float* __restrict__ gb)
{
    const int combo = blockIdx.x;     // dir*2 + gate
    const int o     = threadIdx.x;    // 0..63
    const int dir   = combo >> 1;
    const int gate  = combo & 1;
    const float* W  = dir ? (gate ? bwh : bwz) : (gate ? fwh : fwz);
    const float* Bv = dir ? (gate ? bbh : bbz) : (gate ? fbh : fbz);
    const float* P  = dir ? bpw : fpw;
    const float* pb = dir ? bpb : fpb;
    float* outw = gw + (size_t)combo*64*67 + o*67;
    for (int k = 0; k < 67; ++k) {
        float acc = 0.f;
        for (int j = 0; j < 64; ++j)
            acc = fmaf(W[o*64 + j], P[j*67 + k], acc);
        outw[k] = acc;
    }
    float accb = Bv[o];
    for (int j = 0; j < 64; ++j) accb = fmaf(W[o*64 + j], pb[j], accb);
    gb[combo*64 + o] = accb;
}

// =====================================================================
// kernel 1: fused scan — folded gates, 2 barriers/segment.
// 512 thr = 8 waves. Per segment i:
//   B { scanAB(i) -> s_A/s_B | t-load(i+1) | G1(i+1) -> s_tenc }
//   A { CARRY(i) (all waves, dbuf s_H) | OUT(i) | GZH(i+1) -> s_seg
//       | x-load(i+2) }
// tenc/scan/out paths bitwise-identical to R21; gate pre-acts use the
// folded (W·P) weights (single bf16 rounding instead of two).
// =====================================================================
#define SSTR 129

__global__ __launch_bounds__(512) void scan_fused(
    const float* __restrict__ x, const float* __restrict__ t,
    const float* __restrict__ mtok,
    const float* __restrict__ te_w1, const float* __restrict__ te_b1,
    const float* __restrict__ te_w2, const float* __restrict__ te_b2,
    const float* __restrict__ gw, const float* __restrict__ gb,
    int b0,
    unsigned short* __restrict__ hf, unsigned short* __restrict__ hb)
{
    __shared__ __align__(16) unsigned short s_tenc[128*72];  // 18432 B
    __shared__ uint32_t s_seg[64*SSTR];                      // 33024 B
    __shared__ float s_A[8][65], s_B[8][65];                 //  4160 B
    __shared__ float s_H[2][64];                             //   512 B
    __shared__ float2 s_wb[64];                              //   512 B
    // total 56640 B (55.3 KB)

    const int rl  = blockIdx.x >> 1;
    const int dir = blockIdx.x & 1;
    const int tid = threadIdx.x;
    const int h   = tid & 63;     // lane
    const int q   = tid >> 6;     // wave 0..7
    const int lq  = h >> 4;
    const int ln  = h & 15;
    const int mq  = q >> 1;       // m-tile pair owner (0..3)
    const int nh  = q & 1;        // n-tile pair owner (0..1)

    const int gx = (b0 + rl) << 11;     // global l base for this b
    unsigned short* out = (dir ? hb : hf) + (size_t)rl * NL * 64;

    // ---- weights (persistent regs, nt-split: this wave's 2 n-tiles) ----
    short8 bte[2][2];
    float bite[2];
#pragma unroll
    for (int ni = 0; ni < 2; ++ni) {
        const int nt = nh*2 + ni;
        const float* row = te_w2 + (nt*16 + ln)*64;
#pragma unroll
        for (int ks = 0; ks < 2; ++ks) bte[ni][ks] = frag8(row + lq*8 + ks*32);
        bite[ni] = te_b2[nt*16 + ln];
    }
    const float* GZ  = gw + (size_t)(dir*2 + 0)*64*67;
    const float* GH  = gw + (size_t)(dir*2 + 1)*64*67;
    const float* BZ2 = gb + (dir*2 + 0)*64;
    const float* BH2 = gb + (dir*2 + 1)*64;
    short8 bgz[2][3], bgh[2][3];
    float biz[2], bih[2];
#pragma unroll
    for (int ni = 0; ni < 2; ++ni) {
        const int nt = nh*2 + ni;
        const float* rz = GZ + (nt*16 + ln)*67;
        const float* rh = GH + (nt*16 + ln)*67;
#pragma unroll
        for (int ks = 0; ks < 2; ++ks) {
            float tz[8], th[8];
#pragma unroll
            for (int j = 0; j < 8; ++j) {
                tz[j] = rz[3 + lq*8 + ks*32 + j];
                th[j] = rh[3 + lq*8 + ks*32 + j];
            }
            bgz[ni][ks] = frag8(tz);
            bgh[ni][ks] = frag8(th);
        }
        {
            float tz[8], th[8];
#pragma unroll
            for (int j = 0; j < 8; ++j) {
                tz[j] = (lq == 0 && j < 3) ? rz[j] : 0.f;
                th[j] = (lq == 0 && j < 3) ? rh[j] : 0.f;
            }
            bgz[ni][2] = frag8(tz);
            bgh[ni][2] = frag8(th);
        }
        biz[ni] = BZ2[nt*16 + ln];
        bih[ni] = BH2[nt*16 + ln];
    }
    const float mt0 = mtok[0], mt1 = mtok[1];

    // ---- phase lambdas ----
    auto G1 = [&](const float* tvv) {  // te1 from s_wb -> tenc GEMM
#pragma unroll
        for (int mi = 0; mi < 2; ++mi) {
            short8 a0, a1;
#pragma unroll
            for (int j = 0; j < 8; ++j) {
                const float2 wb0 = s_wb[lq*8 + j];
                const float2 wb1 = s_wb[lq*8 + 32 + j];
                a0[j] = (short)bf1(fmaxf(fmaf(tvv[mi], wb0.x, wb0.y), 0.f));
                a1[j] = (short)bf1(fmaxf(fmaf(tvv[mi], wb1.x, wb1.y), 0.f));
            }
#pragma unroll
            for (int ni = 0; ni < 2; ++ni) {
                f32x4 c = {0.f, 0.f, 0.f, 0.f};
                c = MFMA16(a0, bte[ni][0], c);
                c = MFMA16(a1, bte[ni][1], c);
                const int o = (nh*2+ni)*16 + ln;
#pragma unroll
                for (int r = 0; r < 4; ++r)
                    s_tenc[((mq*2+mi)*16 + lq*4 + r)*72 + o] = bf1(c[r] + bite[ni]);
            }
        }
    };
    auto GZH = [&](const float* xr0_, const float* xr1_, const float* xmc_) {
        // [tenc|x3] x folded gate weights -> activations -> s_seg
#pragma unroll
        for (int mi = 0; mi < 2; ++mi) {
            const int mrow = (mq*2+mi)*16 + ln;
            const short8 a0 = *(const short8*)(s_tenc + mrow*72 + lq*8);
            const short8 a1 = *(const short8*)(s_tenc + mrow*72 + lq*8 + 32);
            short8 a2 = {0,0,0,0,0,0,0,0};
            if (lq == 0) {
                const float mc  = xmc_[mi];
                const float x0m = (mc == 0.f) ? mt0 : xr0_[mi];
                const float x1m = (mc == 0.f) ? mt1 : xr1_[mi];
                a2[0] = (short)bf1(x0m);
                a2[1] = (short)bf1(x1m);
                a2[2] = (short)bf1(mc);
            }
#pragma unroll
            for (int ni = 0; ni < 2; ++ni) {
                f32x4 cz  = {0.f, 0.f, 0.f, 0.f};
                f32x4 ch2 = {0.f, 0.f, 0.f, 0.f};
                cz  = MFMA16(a0, bgz[ni][0], cz);
                cz  = MFMA16(a1, bgz[ni][1], cz);
                cz  = MFMA16(a2, bgz[ni][2], cz);
                ch2 = MFMA16(a0, bgh[ni][0], ch2);
                ch2 = MFMA16(a1, bgh[ni][1], ch2);
                ch2 = MFMA16(a2, bgh[ni][2], ch2);
                const int hcol = (nh*2+ni)*16 + ln;
#pragma unroll
                for (int r = 0; r < 4; ++r) {
                    const float az = cz[r]  + biz[ni];
                    const float ah = ch2[r] + bih[ni];
                    const float z  = __builtin_amdgcn_rcpf(1.f + __expf(-az));
                    const float cc = fminf(fmaxf(ah, -15.f), 15.f);
                    const float e2 = __expf(2.f * cc);
                    const float th = 1.f - 2.f * __builtin_amdgcn_rcpf(e2 + 1.f);
                    s_seg[hcol*SSTR + (mq*2+mi)*16 + lq*4 + r] = pk2(1.f - z, z * th);
                }
            }
        }
    };

    if (tid < 64) {
        s_H[0][tid] = 0.f;
        s_wb[tid] = make_float2(te_w1[tid], te_b1[tid]);
    }
    barrier_lds();              // s_wb visible

    // ---- prologue ----
    const int s0 = dir ? 15 : 0;
    const int s1 = dir ? 14 : 1;
    {
        float tv0[2];
#pragma unroll
        for (int mi = 0; mi < 2; ++mi)
            tv0[mi] = t[gx + s0*128 + (mq*2+mi)*16 + ln];
        G1(tv0);               // s_tenc(s0)
    }
    float xr0_[2], xr1_[2], xmc_[2];
    if (lq == 0) {
#pragma unroll
        for (int mi = 0; mi < 2; ++mi) {
            const float* xp = x + (size_t)(gx + s0*128 + (mq*2+mi)*16 + ln)*3;
            xr0_[mi] = xp[0]; xr1_[mi] = xp[1]; xmc_[mi] = xp[2];
        }
    }
    barrier_lds();             // s_tenc(s0) ready
    GZH(xr0_, xr1_, xmc_);     // s_seg(s0)
    float tvn[2];
#pragma unroll
    for (int mi = 0; mi < 2; ++mi)
        tvn[mi] = t[gx + s1*128 + (mq*2+mi)*16 + ln];
    if (lq == 0) {
#pragma unroll
        for (int mi = 0; mi < 2; ++mi) {
            const float* xp = x + (size_t)(gx + s1*128 + (mq*2+mi)*16 + ln)*3;
            xr0_[mi] = xp[0]; xr1_[mi] = xp[1]; xmc_[mi] = xp[2];
        }
    }
    barrier_lds();             // s_seg(s0) ready

    uint32_t regs[16];
    int p = 0;

#pragma unroll 1
    for (int si = 0; si < 16; ++si) {
        const int s  = dir ? (15 - si) : si;
        // ---- phase B(si): scanAB + G1(si+1) ----
        {
            float A = 1.f, Bc = 0.f;
#pragma unroll
            for (int i = 0; i < 16; ++i) {
                const int g = q*16 + i;
                const int xx = dir ? (127 - g) : g;
                const uint32_t uab = s_seg[h*SSTR + xx];
                regs[i] = uab;
                Bc = fmaf(bflo(uab), Bc, bfhi(uab));
                A *= bflo(uab);
            }
            s_A[q][h] = A; s_B[q][h] = Bc;
        }
        if (si < 15) G1(tvn);
        barrier_lds();
        // ---- phase A: CARRY(si) all waves | OUT(si) | GZH(si+1) ----
        float Hin;
        {
            float H = s_H[p][h];
#pragma unroll
            for (int qq = 0; qq < 8; ++qq) {
                if (qq == q) Hin = H;
                H = fmaf(s_A[qq][h], H, s_B[qq][h]);
            }
            if (q == 0) s_H[p ^ 1][h] = H;
        }
        p ^= 1;
        {
            const int l0 = s * 128;
            float hv = Hin;
#pragma unroll
            for (int i = 0; i < 16; ++i) {
                const int g = q*16 + i;
                const int xx = dir ? (127 - g) : g;
                out[(size_t)(l0 + xx)*64 + h] = bf1(hv);
                hv = fmaf(bflo(regs[i]), hv, bfhi(regs[i]));
            }
        }
        if (si < 15) {
            GZH(xr0_, xr1_, xmc_);            // s_seg(si+1)
            if (si < 14) {
                const int s2 = dir ? (13 - si) : (si + 2);
#pragma unroll
                for (int mi = 0; mi < 2; ++mi)
                    tvn[mi] = t[gx + s2*128 + (mq*2+mi)*16 + ln];
                if (lq == 0) {
#pragma unroll
                    for (int mi = 0; mi < 2; ++mi) {
                        const float* xp = x + (size_t)(gx + s2*128 + (mq*2+mi)*16 + ln)*3;
                        xr0_[mi] = xp[0]; xr1_[mi] = xp[1]; xmc_[mi] = xp[2];
                    }
                }
            }
        }
        barrier_lds();
    }
}

// =====================================================================
// kernel 2: MFMA head — R15/R19 shape (best measured ~150us).
// =====================================================================
__global__ __launch_bounds__(256, 3) void head_kernel(
    const float* __restrict__ x, const float* __restrict__ t,
    const float* __restrict__ te_w1, const float* __restrict__ te_b1,
    const float* __restrict__ te_w2, const float* __restrict__ te_b2,
    const unsigned short* __restrict__ hf, const unsigned short* __restrict__ hb,
    const float* __restrict__ w1, const float* __restrict__ b1,
    const float* __restrict__ w2, const float* __restrict__ b2,
    int b0,
    float* __restrict__ out)
{
    __shared__ __align__(16) unsigned short s_a[64*200];   // 25600 B
    __shared__ __align__(16) unsigned short s_te1[64*72];  //  9216 B
    __shared__ float s_part[4][64];                        //  1024 B
    __shared__ float s_mc[64];                             //   256 B

    const int tid = threadIdx.x;
    const int w   = tid >> 6;
    const int l   = tid & 63;
    const int lq  = l >> 4;
    const int ln  = l & 15;

    short8 bw1[2][6];
    float b1v[2], w2v[2];
#pragma unroll
    for (int p = 0; p < 2; ++p) {
        const int o = (2*w + p)*16 + ln;
        const float* row = w1 + o*192;
#pragma unroll
        for (int ks = 0; ks < 6; ++ks) bw1[p][ks] = frag8(row + lq*8 + ks*32);
        b1v[p] = b1[o];
        w2v[p] = w2[o];
    }
    short8 bte[2];
    {
        const float* row = te_w2 + (w*16 + ln)*64;
#pragma unroll
        for (int ks = 0; ks < 2; ++ks) bte[ks] = frag8(row + lq*8 + ks*32);
    }
    const float bias_te = te_b2[w*16 + ln];
    const float bias2 = b2[0];

    const int baseposl = blockIdx.x * 256;

    auto A = [&](int ch) {    // mc + te1 staging
        const int gbase = (b0 << 11) + baseposl + ch*64;
        if (tid < 64) s_mc[tid] = x[(size_t)(gbase + tid)*3 + 2];
        const int pos = tid & 63;
        const float tv = t[gbase + pos];
        const int k0 = (tid >> 6) * 16;
        uint32_t* dst = (uint32_t*)(s_te1 + pos*72 + k0);
#pragma unroll
        for (int kk = 0; kk < 16; kk += 2) {
            float v0 = fmaxf(fmaf(tv, te_w1[k0+kk],   te_b1[k0+kk]),   0.f);
            float v1 = fmaxf(fmaf(tv, te_w1[k0+kk+1], te_b1[k0+kk+1]), 0.f);
            dst[kk >> 1] = pk2(v0, v1);
        }
    };
    auto Bp = [&](int ch) {   // uint4 gather + tenc GEMM (disjoint s_a cols)
        const int chbase = baseposl + ch*64;
        const int ll0 = chbase & 2047;
        const int bl  = chbase >> 11;
        const size_t rowbase = (size_t)bl * NL * 64;
#pragma unroll
        for (int rep = 0; rep < 4; ++rep) {
            const int idx = rep*256 + tid;
            const int seg = idx >> 9;
            const int row = (idx >> 3) & 63;
            const int c   = idx & 7;
            const bool unm = s_mc[row] > 0.f;
            const uint4* src = (seg == 0)
                ? (const uint4*)(hf + rowbase + (size_t)(unm ? (ll0+row) : (NL-1))*64)
                : (const uint4*)(hb + rowbase + (size_t)(unm ? (ll0+row) : 0)*64);
            ((uint4*)s_a)[row*25 + seg*8 + c] = src[c];
        }
        const int o = w*16 + ln;
#pragma unroll
        for (int mt = 0; mt < 4; ++mt) {
            f32x4 c = {0.f, 0.f, 0.f, 0.f};
#pragma unroll
            for (int ks = 0; ks < 2; ++ks) {
                const short8 a = *(const short8*)(s_te1 + (mt*16+ln)*72 + lq*8 + ks*32);
                c = MFMA16(a, bte[ks], c);
            }
#pragma unroll
            for (int r = 0; r < 4; ++r) {
                const int m = mt*16 + lq*4 + r;
                s_a[m*200 + 128 + o] = bf1(c[r] + bias_te);
            }
        }
    };
    auto Cp = [&]() {         // GEMM1 + relu*w2 + quad shuffle-reduce
#pragma unroll
        for (int mt = 0; mt < 4; ++mt) {
            short8 af[6];
#pragma unroll
            for (int ks = 0; ks < 6; ++ks)
                af[ks] = *(const short8*)(s_a + (mt*16+ln)*200 + lq*8 + ks*32);
            float vs[4] = {0.f, 0.f, 0.f, 0.f};
#pragma unroll
            for (int p = 0; p < 2; ++p) {
                f32x4 c = {0.f, 0.f, 0.f, 0.f};
#pragma unroll
                for (int ks = 0; ks < 6; ++ks) c = MFMA16(af[ks], bw1[p][ks], c);
#pragma unroll
                for (int r = 0; r < 4; ++r)
                    vs[r] += fmaxf(c[r] + b1v[p], 0.f) * w2v[p];
            }
#pragma unroll
            for (int mask = 1; mask < 16; mask <<= 1) {
#pragma unroll
                for (int r = 0; r < 4; ++r)
                    vs[r] += __shfl_xor(vs[r], mask);
            }
            if (ln == 0) {
#pragma unroll
                for (int r = 0; r < 4; ++r)
                    s_part[w][mt*16 + lq*4 + r] = vs[r];
            }
        }
    };
    auto Dp = [&](int ch) {   // out write
        const int gbase = (b0 << 11) + baseposl + ch*64;
        if (tid < 64) {
            out[gbase + tid] = s_part[0][tid] + s_part[1][tid]
                             + s_part[2][tid] + s_part[3][tid] + bias2;
        }
    };

    A(0);
    barrier_lds();
#pragma unroll 1
    for (int ch = 0; ch < 4; ++ch) {
        Bp(ch);
        barrier_lds();
        Cp();
        barrier_lds();
        Dp(ch);                      // reads s_part
        if (ch < 3) A(ch + 1);       // writes s_mc/s_te1 — disjoint, overlapped
        barrier_lds();
    }
}

extern "C" void kernel_launch(void* const* d_in, const int* in_sizes, int n_in,
                              void* d_out, int out_size, void* d_ws, size_t ws_size,
                              hipStream_t stream)
{
    const float* x     = (const float*)d_in[0];
    const float* t     = (const float*)d_in[1];
    const float* mtok  = (const float*)d_in[2];
    const float* te_w1 = (const float*)d_in[3];
    const float* te_b1 = (const float*)d_in[4];
    const float* te_w2 = (const float*)d_in[5];
    const float* te_b2 = (const float*)d_in[6];
    const float* fpw   = (const float*)d_in[7];
    const float* fpb   = (const float*)d_in[8];
    const float* bpw   = (const float*)d_in[9];
    const float* bpb   = (const float*)d_in[10];
    const float* fwz   = (const float*)d_in[11];
    const float* fbz   = (const float*)d_in[12];
    const float* fwh   = (const float*)d_in[13];
    const float* fbh   = (const float*)d_in[14];
    const float* bwz   = (const float*)d_in[15];
    const float* bbz   = (const float*)d_in[16];
    const float* bwh   = (const float*)d_in[17];
    const float* bbh   = (const float*)d_in[18];
    const float* w1    = (const float*)d_in[19];
    const float* b1    = (const float*)d_in[20];
    const float* w2    = (const float*)d_in[21];
    const float* b2    = (const float*)d_in[22];

    // per b: h (2 dirs) = 512 KB; tail: folded weights (4x64x67 f32 + 4x64 f32)
    const size_t tail  = (size_t)4*64*67*4 + (size_t)4*64*4;
    const size_t per_b = 524288ull;
    int Bg = NB;
    while ((size_t)Bg * per_b + tail > ws_size && Bg > 1) Bg >>= 1;
    const int nG = NB / Bg;

    char* ws = (char*)d_ws;
    unsigned short* hf = (unsigned short*)ws;
    unsigned short* hb = hf + (size_t)Bg * NL * 64;
    float* gw = (float*)(hb + (size_t)Bg * NL * 64);
    float* gb = gw + (size_t)4*64*67;

    fold_weights<<<4, 64, 0, stream>>>(
        fpw, fpb, bpw, bpb, fwz, fbz, fwh, fbh, bwz, bbz, bwh, bbh, gw, gb);

    for (int g = 0; g < nG; ++g) {
        const int b0 = g * Bg;

        scan_fused<<<2 * Bg, 512, 0, stream>>>(
            x, t, mtok, te_w1, te_b1, te_w2, te_b2,
            gw, gb, b0, hf, hb);

        head_kernel<<<8 * Bg, 256, 0, stream>>>(
            x, t, te_w1, te_b1, te_w2, te_b2,
            hf, hb, w1, b1, w2, b2, b0, (float*)d_out);
    }
}

// Round 13
// 319.091 us; speedup vs baseline: 1.2639x; 1.2639x over previous
//
#include <hip/hip_runtime.h>
#include <stdint.h>

// Problem constants (B=256, L=2048, H=64, TE=64)
#define NB 256
#define NL 2048

typedef __attribute__((ext_vector_type(8))) short short8;
typedef __attribute__((ext_vector_type(4))) float f32x4;
#define MFMA16(a,b,c) __builtin_amdgcn_mfma_f32_16x16x32_bf16(a,b,c,0,0,0)

// ---------- bf16 helpers ----------
// R16: gates into scan (371->334). R17 spill 484. R18/19: 317 best.
// R20/R22/R23: occupancy hints => hipcc pins VGPR=64 => spill. CLOSED.
// R24/R25: head async-gather neutral / global-A regressed. Head = R15.
// R26: scan fold (W·P) + merged GZH + all-wave dbuf carry: scan
//      168->141us, LDS 56.8KB (co-residency still did NOT unlock —
//      hypothesis dead). BUT naive fold_weights (4 blk x 64 thr, serial
//      67x64 global-chain) cost ~120us latency-bound => total 403.
// R27: fold_weights parallelized — 256 thr/blk, P staged in LDS
//      (broadcast reads), W row in regs, 17-k slice per thread. Same
//      summation order => bitwise-identical gw/gb. Scan/head untouched.
static __device__ __forceinline__ unsigned short f2bf(float f) {
    union { float f; uint32_t u; } v; v.f = f;
    uint32_t u = v.u;
    uint32_t r = u + 0x7fffu + ((u >> 16) & 1u);
    return (unsigned short)(r >> 16);
}
static __device__ __forceinline__ float bflo(uint32_t u) {
    union { uint32_t u; float f; } v; v.u = u << 16; return v.f;
}
static __device__ __forceinline__ float bfhi(uint32_t u) {
    union { uint32_t u; float f; } v; v.u = u & 0xffff0000u; return v.f;
}
#if __has_builtin(__builtin_amdgcn_cvt_pk_bf16_f32)
typedef __attribute__((ext_vector_type(2))) __bf16 bf16x2_t;
static __device__ __forceinline__ uint32_t pk2(float lo, float hi) {
    union { bf16x2_t v; uint32_t u; } c;
    c.v = __builtin_amdgcn_cvt_pk_bf16_f32(lo, hi);
    return c.u;
}
static __device__ __forceinline__ unsigned short bf1(float v) {
    union { bf16x2_t v; uint32_t u; } c;
    c.v = __builtin_amdgcn_cvt_pk_bf16_f32(v, v);
    return (unsigned short)(c.u & 0xffffu);
}
#else
static __device__ __forceinline__ uint32_t pk2(float lo, float hi) {
    return ((uint32_t)f2bf(hi) << 16) | (uint32_t)f2bf(lo);
}
static __device__ __forceinline__ unsigned short bf1(float v) { return f2bf(v); }
#endif
static __device__ __forceinline__ short8 frag8(const float* p) {
    short8 r;
#pragma unroll
    for (int j = 0; j < 8; ++j) r[j] = (short)f2bf(p[j]);
    return r;
}

// LDS-only barrier: global stores/loads stay in flight across it.
static __device__ __forceinline__ void barrier_lds() {
    asm volatile("s_waitcnt lgkmcnt(0)" ::: "memory");
    __builtin_amdgcn_s_barrier();
}

// =====================================================================
// kernel 0: fold gate weights — G = W·P (64x67 fp32), b' = b + W·pb.
// R27: 256 thr/block; P in LDS (stride 68, wave-uniform broadcast);
// W row in 64 regs; thread (o = tid&63, kq = tid>>6) computes k-slice.
// Summation order (ascending j, fmaf) identical to R26 -> same bits.
// =====================================================================
__global__ __launch_bounds__(256) void fold_weights(
    const float* __restrict__ fpw, const float* __restrict__ fpb,
    const float* __restrict__ bpw, const float* __restrict__ bpb,
    const float* __restrict__ fwz, const float* __restrict__ fbz,
    const float* __restrict__ fwh, const float* __restrict__ fbh,
    const float* __restrict__ bwz, const float* __restrict__ bbz,
    const float* __restrict__ bwh, const float* __restrict__ bbh,
    float* __restrict__ gw, float* __restrict__ gb)
{
    __shared__ float sP[64*68];       // 17408 B
    __shared__ float sPb[64];

    const int combo = blockIdx.x;     // dir*2 + gate
    const int tid   = threadIdx.x;
    const int dir   = combo >> 1;
    const int gate  = combo & 1;
    const float* W  = dir ? (gate ? bwh : bwz) : (gate ? fwh : fwz);
    const float* Bv = dir ? (gate ? bbh : bbz) : (gate ? fbh : fbz);
    const float* P  = dir ? bpw : fpw;
    const float* pb = dir ? bpb : fpb;

    for (int i = tid; i < 64*67; i += 256)
        sP[(i/67)*68 + (i%67)] = P[i];
    if (tid < 64) sPb[tid] = pb[tid];
    __syncthreads();

    const int o  = tid & 63;
    const int kq = tid >> 6;          // 0..3 -> k in [kq*17, min(67,kq*17+17))
    float wr[64];
#pragma unroll
    for (int j = 0; j < 64; ++j) wr[j] = W[o*64 + j];

    float* outw = gw + (size_t)combo*64*67 + o*67;
    const int k0 = kq*17, k1 = (k0 + 17 < 67) ? (k0 + 17) : 67;
    for (int k = k0; k < k1; ++k) {
        float acc = 0.f;
#pragma unroll
        for (int j = 0; j < 64; ++j) acc = fmaf(wr[j], sP[j*68 + k], acc);
        outw[k] = acc;
    }
    if (kq == 0) {
        float accb = Bv[o];
#pragma unroll
        for (int j = 0; j < 64; ++j) accb = fmaf(wr[j], sPb[j], accb);
        gb[combo*64 + o] = accb;
    }
}

// =====================================================================
// kernel 1: fused scan — folded gates, 2 barriers/segment (R26 shape).
// =====================================================================
#define SSTR 129

__global__ __launch_bounds__(512) void scan_fused(
    const float* __restrict__ x, const float* __restrict__ t,
    const float* __restrict__ mtok,
    const float* __restrict__ te_w1, const float* __restrict__ te_b1,
    const float* __restrict__ te_w2, const float* __restrict__ te_b2,
    const float* __restrict__ gw, const float* __restrict__ gb,
    int b0,
    unsigned short* __restrict__ hf, unsigned short* __restrict__ hb)
{
    __shared__ __align__(16) unsigned short s_tenc[128*72];  // 18432 B
    __shared__ uint32_t s_seg[64*SSTR];                      // 33024 B
    __shared__ float s_A[8][65], s_B[8][65];                 //  4160 B
    __shared__ float s_H[2][64];                             //   512 B
    __shared__ float2 s_wb[64];                              //   512 B

    const int rl  = blockIdx.x >> 1;
    const int dir = blockIdx.x & 1;
    const int tid = threadIdx.x;
    const int h   = tid & 63;     // lane
    const int q   = tid >> 6;     // wave 0..7
    const int lq  = h >> 4;
    const int ln  = h & 15;
    const int mq  = q >> 1;       // m-tile pair owner (0..3)
    const int nh  = q & 1;        // n-tile pair owner (0..1)

    const int gx = (b0 + rl) << 11;     // global l base for this b
    unsigned short* out = (dir ? hb : hf) + (size_t)rl * NL * 64;

    // ---- weights (persistent regs, nt-split: this wave's 2 n-tiles) ----
    short8 bte[2][2];
    float bite[2];
#pragma unroll
    for (int ni = 0; ni < 2; ++ni) {
        const int nt = nh*2 + ni;
        const float* row = te_w2 + (nt*16 + ln)*64;
#pragma unroll
        for (int ks = 0; ks < 2; ++ks) bte[ni][ks] = frag8(row + lq*8 + ks*32);
        bite[ni] = te_b2[nt*16 + ln];
    }
    const float* GZ  = gw + (size_t)(dir*2 + 0)*64*67;
    const float* GH  = gw + (size_t)(dir*2 + 1)*64*67;
    const float* BZ2 = gb + (dir*2 + 0)*64;
    const float* BH2 = gb + (dir*2 + 1)*64;
    short8 bgz[2][3], bgh[2][3];
    float biz[2], bih[2];
#pragma unroll
    for (int ni = 0; ni < 2; ++ni) {
        const int nt = nh*2 + ni;
        const float* rz = GZ + (nt*16 + ln)*67;
        const float* rh = GH + (nt*16 + ln)*67;
#pragma unroll
        for (int ks = 0; ks < 2; ++ks) {
            float tz[8], th[8];
#pragma unroll
            for (int j = 0; j < 8; ++j) {
                tz[j] = rz[3 + lq*8 + ks*32 + j];
                th[j] = rh[3 + lq*8 + ks*32 + j];
            }
            bgz[ni][ks] = frag8(tz);
            bgh[ni][ks] = frag8(th);
        }
        {
            float tz[8], th[8];
#pragma unroll
            for (int j = 0; j < 8; ++j) {
                tz[j] = (lq == 0 && j < 3) ? rz[j] : 0.f;
                th[j] = (lq == 0 && j < 3) ? rh[j] : 0.f;
            }
            bgz[ni][2] = frag8(tz);
            bgh[ni][2] = frag8(th);
        }
        biz[ni] = BZ2[nt*16 + ln];
        bih[ni] = BH2[nt*16 + ln];
    }
    const float mt0 = mtok[0], mt1 = mtok[1];

    // ---- phase lambdas ----
    auto G1 = [&](const float* tvv) {  // te1 from s_wb -> tenc GEMM
#pragma unroll
        for (int mi = 0; mi < 2; ++mi) {
            short8 a0, a1;
#pragma unroll
            for (int j = 0; j < 8; ++j) {
                const float2 wb0 = s_wb[lq*8 + j];
                const float2 wb1 = s_wb[lq*8 + 32 + j];
                a0[j] = (short)bf1(fmaxf(fmaf(tvv[mi], wb0.x, wb0.y), 0.f));
                a1[j] = (short)bf1(fmaxf(fmaf(tvv[mi], wb1.x, wb1.y), 0.f));
            }
#pragma unroll
            for (int ni = 0; ni < 2; ++ni) {
                f32x4 c = {0.f, 0.f, 0.f, 0.f};
                c = MFMA16(a0, bte[ni][0], c);
                c = MFMA16(a1, bte[ni][1], c);
                const int o = (nh*2+ni)*16 + ln;
#pragma unroll
                for (int r = 0; r < 4; ++r)
                    s_tenc[((mq*2+mi)*16 + lq*4 + r)*72 + o] = bf1(c[r] + bite[ni]);
            }
        }
    };
    auto GZH = [&](const float* xr0_, const float* xr1_, const float* xmc_) {
        // [tenc|x3] x folded gate weights -> activations -> s_seg
#pragma unroll
        for (int mi = 0; mi < 2; ++mi) {
            const int mrow = (mq*2+mi)*16 + ln;
            const short8 a0 = *(const short8*)(s_tenc + mrow*72 + lq*8);
            const short8 a1 = *(const short8*)(s_tenc + mrow*72 + lq*8 + 32);
            short8 a2 = {0,0,0,0,0,0,0,0};
            if (lq == 0) {
                const float mc  = xmc_[mi];
                const float x0m = (mc == 0.f) ? mt0 : xr0_[mi];
                const float x1m = (mc == 0.f) ? mt1 : xr1_[mi];
                a2[0] = (short)bf1(x0m);
                a2[1] = (short)bf1(x1m);
                a2[2] = (short)bf1(mc);
            }
#pragma unroll
            for (int ni = 0; ni < 2; ++ni) {
                f32x4 cz  = {0.f, 0.f, 0.f, 0.f};
                f32x4 ch2 = {0.f, 0.f, 0.f, 0.f};
                cz  = MFMA16(a0, bgz[ni][0], cz);
                cz  = MFMA16(a1, bgz[ni][1], cz);
                cz  = MFMA16(a2, bgz[ni][2], cz);
                ch2 = MFMA16(a0, bgh[ni][0], ch2);
                ch2 = MFMA16(a1, bgh[ni][1], ch2);
                ch2 = MFMA16(a2, bgh[ni][2], ch2);
                const int hcol = (nh*2+ni)*16 + ln;
#pragma unroll
                for (int r = 0; r < 4; ++r) {
                    const float az = cz[r]  + biz[ni];
                    const float ah = ch2[r] + bih[ni];
                    const float z  = __builtin_amdgcn_rcpf(1.f + __expf(-az));
                    const float cc = fminf(fmaxf(ah, -15.f), 15.f);
                    const float e2 = __expf(2.f * cc);
                    const float th = 1.f - 2.f * __builtin_amdgcn_rcpf(e2 + 1.f);
                    s_seg[hcol*SSTR + (mq*2+mi)*16 + lq*4 + r] = pk2(1.f - z, z * th);
                }
            }
        }
    };

    if (tid < 64) {
        s_H[0][tid] = 0.f;
        s_wb[tid] = make_float2(te_w1[tid], te_b1[tid]);
    }
    barrier_lds();              // s_wb visible

    // ---- prologue ----
    const int s0 = dir ? 15 : 0;
    const int s1 = dir ? 14 : 1;
    {
        float tv0[2];
#pragma unroll
        for (int mi = 0; mi < 2; ++mi)
            tv0[mi] = t[gx + s0*128 + (mq*2+mi)*16 + ln];
        G1(tv0);               // s_tenc(s0)
    }
    float xr0_[2], xr1_[2], xmc_[2];
    if (lq == 0) {
#pragma unroll
        for (int mi = 0; mi < 2; ++mi) {
            const float* xp = x + (size_t)(gx + s0*128 + (mq*2+mi)*16 + ln)*3;
            xr0_[mi] = xp[0]; xr1_[mi] = xp[1]; xmc_[mi] = xp[2];
        }
    }
    barrier_lds();             // s_tenc(s0) ready
    GZH(xr0_, xr1_, xmc_);     // s_seg(s0)
    float tvn[2];
#pragma unroll
    for (int mi = 0; mi < 2; ++mi)
        tvn[mi] = t[gx + s1*128 + (mq*2+mi)*16 + ln];
    if (lq == 0) {
#pragma unroll
        for (int mi = 0; mi < 2; ++mi) {
            const float* xp = x + (size_t)(gx + s1*128 + (mq*2+mi)*16 + ln)*3;
            xr0_[mi] = xp[0]; xr1_[mi] = xp[1]; xmc_[mi] = xp[2];
        }
    }
    barrier_lds();             // s_seg(s0) ready

    uint32_t regs[16];
    int p = 0;

#pragma unroll 1
    for (int si = 0; si < 16; ++si) {
        const int s  = dir ? (15 - si) : si;
        // ---- phase B(si): scanAB + G1(si+1) ----
        {
            float A = 1.f, Bc = 0.f;
#pragma unroll
            for (int i = 0; i < 16; ++i) {
                const int g = q*16 + i;
                const int xx = dir ? (127 - g) : g;
                const uint32_t uab = s_seg[h*SSTR + xx];
                regs[i] = uab;
                Bc = fmaf(bflo(uab), Bc, bfhi(uab));
                A *= bflo(uab);
            }
            s_A[q][h] = A; s_B[q][h] = Bc;
        }
        if (si < 15) G1(tvn);
        barrier_lds();
        // ---- phase A: CARRY(si) all waves | OUT(si) | GZH(si+1) ----
        float Hin;
        {
            float H = s_H[p][h];
#pragma unroll
            for (int qq = 0; qq < 8; ++qq) {
                if (qq == q) Hin = H;
                H = fmaf(s_A[qq][h], H, s_B[qq][h]);
            }
            if (q == 0) s_H[p ^ 1][h] = H;
        }
        p ^= 1;
        {
            const int l0 = s * 128;
            float hv = Hin;
#pragma unroll
            for (int i = 0; i < 16; ++i) {
                const int g = q*16 + i;
                const int xx = dir ? (127 - g) : g;
                out[(size_t)(l0 + xx)*64 + h] = bf1(hv);
                hv = fmaf(bflo(regs[i]), hv, bfhi(regs[i]));
            }
        }
        if (si < 15) {
            GZH(xr0_, xr1_, xmc_);            // s_seg(si+1)
            if (si < 14) {
                const int s2 = dir ? (13 - si) : (si + 2);
#pragma unroll
                for (int mi = 0; mi < 2; ++mi)
                    tvn[mi] = t[gx + s2*128 + (mq*2+mi)*16 + ln];
                if (lq == 0) {
#pragma unroll
                    for (int mi = 0; mi < 2; ++mi) {
                        const float* xp = x + (size_t)(gx + s2*128 + (mq*2+mi)*16 + ln)*3;
                        xr0_[mi] = xp[0]; xr1_[mi] = xp[1]; xmc_[mi] = xp[2];
                    }
                }
            }
        }
        barrier_lds();
    }
}

// =====================================================================
// kernel 2: MFMA head — R15/R19 shape (best measured ~135-150us).
// =====================================================================
__global__ __launch_bounds__(256, 3) void head_kernel(
    const float* __restrict__ x, const float* __restrict__ t,
    const float* __restrict__ te_w1, const float* __restrict__ te_b1,
    const float* __restrict__ te_w2, const float* __restrict__ te_b2,
    const unsigned short* __restrict__ hf, const unsigned short* __restrict__ hb,
    const float* __restrict__ w1, const float* __restrict__ b1,
    const float* __restrict__ w2, const float* __restrict__ b2,
    int b0,
    float* __restrict__ out)
{
    __shared__ __align__(16) unsigned short s_a[64*200];   // 25600 B
    __shared__ __align__(16) unsigned short s_te1[64*72];  //  9216 B
    __shared__ float s_part[4][64];                        //  1024 B
    __shared__ float s_mc[64];                             //   256 B

    const int tid = threadIdx.x;
    const int w   = tid >> 6;
    const int l   = tid & 63;
    const int lq  = l >> 4;
    const int ln  = l & 15;

    short8 bw1[2][6];
    float b1v[2], w2v[2];
#pragma unroll
    for (int p = 0; p < 2; ++p) {
        const int o = (2*w + p)*16 + ln;
        const float* row = w1 + o*192;
#pragma unroll
        for (int ks = 0; ks < 6; ++ks) bw1[p][ks] = frag8(row + lq*8 + ks*32);
        b1v[p] = b1[o];
        w2v[p] = w2[o];
    }
    short8 bte[2];
    {
        const float* row = te_w2 + (w*16 + ln)*64;
#pragma unroll
        for (int ks = 0; ks < 2; ++ks) bte[ks] = frag8(row + lq*8 + ks*32);
    }
    const float bias_te = te_b2[w*16 + ln];
    const float bias2 = b2[0];

    const int baseposl = blockIdx.x * 256;

    auto A = [&](int ch) {    // mc + te1 staging
        const int gbase = (b0 << 11) + baseposl + ch*64;
        if (tid < 64) s_mc[tid] = x[(size_t)(gbase + tid)*3 + 2];
        const int pos = tid & 63;
        const float tv = t[gbase + pos];
        const int k0 = (tid >> 6) * 16;
        uint32_t* dst = (uint32_t*)(s_te1 + pos*72 + k0);
#pragma unroll
        for (int kk = 0; kk < 16; kk += 2) {
            float v0 = fmaxf(fmaf(tv, te_w1[k0+kk],   te_b1[k0+kk]),   0.f);
            float v1 = fmaxf(fmaf(tv, te_w1[k0+kk+1], te_b1[k0+kk+1]), 0.f);
            dst[kk >> 1] = pk2(v0, v1);
        }
    };
    auto Bp = [&](int ch) {   // uint4 gather + tenc GEMM (disjoint s_a cols)
        const int chbase = baseposl + ch*64;
        const int ll0 = chbase & 2047;
        const int bl  = chbase >> 11;
        const size_t rowbase = (size_t)bl * NL * 64;
#pragma unroll
        for (int rep = 0; rep < 4; ++rep) {
            const int idx = rep*256 + tid;
            const int seg = idx >> 9;
            const int row = (idx >> 3) & 63;
            const int c   = idx & 7;
            const bool unm = s_mc[row] > 0.f;
            const uint4* src = (seg == 0)
                ? (const uint4*)(hf + rowbase + (size_t)(unm ? (ll0+row) : (NL-1))*64)
                : (const uint4*)(hb + rowbase + (size_t)(unm ? (ll0+row) : 0)*64);
            ((uint4*)s_a)[row*25 + seg*8 + c] = src[c];
        }
        const int o = w*16 + ln;
#pragma unroll
        for (int mt = 0; mt < 4; ++mt) {
            f32x4 c = {0.f, 0.f, 0.f, 0.f};
#pragma unroll
            for (int ks = 0; ks < 2; ++ks) {
                const short8 a = *(const short8*)(s_te1 + (mt*16+ln)*72 + lq*8 + ks*32);
                c = MFMA16(a, bte[ks], c);
            }
#pragma unroll
            for (int r = 0; r < 4; ++r) {
                const int m = mt*16 + lq*4 + r;
                s_a[m*200 + 128 + o] = bf1(c[r] + bias_te);
            }
        }
    };
    auto Cp = [&]() {         // GEMM1 + relu*w2 + quad shuffle-reduce
#pragma unroll
        for (int mt = 0; mt < 4; ++mt) {
            short8 af[6];
#pragma unroll
            for (int ks = 0; ks < 6; ++ks)
                af[ks] = *(const short8*)(s_a + (mt*16+ln)*200 + lq*8 + ks*32);
            float vs[4] = {0.f, 0.f, 0.f, 0.f};
#pragma unroll
            for (int p = 0; p < 2; ++p) {
                f32x4 c = {0.f, 0.f, 0.f, 0.f};
#pragma unroll
                for (int ks = 0; ks < 6; ++ks) c = MFMA16(af[ks], bw1[p][ks], c);
#pragma unroll
                for (int r = 0; r < 4; ++r)
                    vs[r] += fmaxf(c[r] + b1v[p], 0.f) * w2v[p];
            }
#pragma unroll
            for (int mask = 1; mask < 16; mask <<= 1) {
#pragma unroll
                for (int r = 0; r < 4; ++r)
                    vs[r] += __shfl_xor(vs[r], mask);
            }
            if (ln == 0) {
#pragma unroll
                for (int r = 0; r < 4; ++r)
                    s_part[w][mt*16 + lq*4 + r] = vs[r];
            }
        }
    };
    auto Dp = [&](int ch) {   // out write
        const int gbase = (b0 << 11) + baseposl + ch*64;
        if (tid < 64) {
            out[gbase + tid] = s_part[0][tid] + s_part[1][tid]
                             + s_part[2][tid] + s_part[3][tid] + bias2;
        }
    };

    A(0);
    barrier_lds();
#pragma unroll 1
    for (int ch = 0; ch < 4; ++ch) {
        Bp(ch);
        barrier_lds();
        Cp();
        barrier_lds();
        Dp(ch);                      // reads s_part
        if (ch < 3) A(ch + 1);       // writes s_mc/s_te1 — disjoint, overlapped
        barrier_lds();
    }
}

extern "C" void kernel_launch(void* const* d_in, const int* in_sizes, int n_in,
                              void* d_out, int out_size, void* d_ws, size_t ws_size,
                              hipStream_t stream)
{
    const float* x     = (const float*)d_in[0];
    const float* t     = (const float*)d_in[1];
    const float* mtok  = (const float*)d_in[2];
    const float* te_w1 = (const float*)d_in[3];
    const float* te_b1 = (const float*)d_in[4];
    const float* te_w2 = (const float*)d_in[5];
    const float* te_b2 = (const float*)d_in[6];
    const float* fpw   = (const float*)d_in[7];
    const float* fpb   = (const float*)d_in[8];
    const float* bpw   = (const float*)d_in[9];
    const float* bpb   = (const float*)d_in[10];
    const float* fwz   = (const float*)d_in[11];
    const float* fbz   = (const float*)d_in[12];
    const float* fwh   = (const float*)d_in[13];
    const float* fbh   = (const float*)d_in[14];
    const float* bwz   = (const float*)d_in[15];
    const float* bbz   = (const float*)d_in[16];
    const float* bwh   = (const float*)d_in[17];
    const float* bbh   = (const float*)d_in[18];
    const float* w1    = (const float*)d_in[19];
    const float* b1    = (const float*)d_in[20];
    const float* w2    = (const float*)d_in[21];
    const float* b2    = (const float*)d_in[22];

    // per b: h (2 dirs) = 512 KB; tail: folded weights (4x64x67 f32 + 4x64 f32)
    const size_t tail  = (size_t)4*64*67*4 + (size_t)4*64*4;
    const size_t per_b = 524288ull;
    int Bg = NB;
    while ((size_t)Bg * per_b + tail > ws_size && Bg > 1) Bg >>= 1;
    const int nG = NB / Bg;

    char* ws = (char*)d_ws;
    unsigned short* hf = (unsigned short*)ws;
    unsigned short* hb = hf + (size_t)Bg * NL * 64;
    float* gw = (float*)(hb + (size_t)Bg * NL * 64);
    float* gb = gw + (size_t)4*64*67;

    fold_weights<<<4, 256, 0, stream>>>(
        fpw, fpb, bpw, bpb, fwz, fbz, fwh, fbh, bwz, bbz, bwh, bbh, gw, gb);

    for (int g = 0; g < nG; ++g) {
        const int b0 = g * Bg;

        scan_fused<<<2 * Bg, 512, 0, stream>>>(
            x, t, mtok, te_w1, te_b1, te_w2, te_b2,
            gw, gb, b0, hf, hb);

        head_kernel<<<8 * Bg, 256, 0, stream>>>(
            x, t, te_w1, te_b1, te_w2, te_b2,
            hf, hb, w1, b1, w2, b2, b0, (float*)d_out);
    }
}